// Round 3
// baseline (1693.371 us; speedup 1.0000x reference)
//
#include <hip/hip_runtime.h>
#include <stdint.h>

#define N_NODES 20000
#define E_EDGES 640000
#define IN_DIM  128
#define HID     256
#define MAXW    512
#define HEADS   32
#define BN_EPS  1e-5f

typedef __attribute__((ext_vector_type(8))) short bf16x8;
typedef __attribute__((ext_vector_type(4))) float f32x4;
typedef unsigned short ushort_t;

static __device__ __forceinline__ float bf2f(ushort_t u){
  union { unsigned int i; float f; } v; v.i = ((unsigned int)u) << 16; return v.f;
}
static __device__ __forceinline__ ushort_t f2bf(float f){
  union { float f; unsigned int i; } v; v.f = f;
  unsigned int r = v.i + 0x7fffu + ((v.i >> 16) & 1u);
  return (ushort_t)(r >> 16);
}

// ---------------- K0: init (agg = x, zero G and s) ----------------
__global__ void k_init(const float* __restrict__ x, float* __restrict__ agg,
                       float* __restrict__ G, float* __restrict__ s){
  int i = blockIdx.x * blockDim.x + threadIdx.x;
  int stride = gridDim.x * blockDim.x;
  const float4* xs = (const float4*)x;
  float4* ad = (float4*)agg;
  for (int j = i; j < N_NODES * IN_DIM / 4; j += stride) ad[j] = xs[j];
  float4 z4 = make_float4(0.f, 0.f, 0.f, 0.f);
  float4* Gd = (float4*)G;
  for (int j = i; j < 256 * 256 / 4; j += stride) Gd[j] = z4;
  if (i < 256) s[i] = 0.f;
}

// ---------------- K-detect: is edge_index stored as int64? ----------------
__global__ void k_detect(const int* __restrict__ ei, int* __restrict__ flag){
  __shared__ int any_nz;
  if (threadIdx.x == 0) any_nz = 0;
  __syncthreads();
  int nz = 0;
  for (int i = threadIdx.x; i < 4096; i += 256)
    if (ei[2 * i + 1] != 0) nz = 1;
  if (nz) atomicOr(&any_nz, 1);
  __syncthreads();
  if (threadIdx.x == 0) flag[0] = (any_nz == 0) ? 1 : 0;   // 1 => int64 layout
}

// ---------------- K1: edge scatter-add (atomics) ----------------
__global__ __launch_bounds__(256) void k_edges(const float* __restrict__ x,
                                               const int* __restrict__ ei,
                                               const int* __restrict__ flag,
                                               float* __restrict__ agg){
  int gw = (blockIdx.x * blockDim.x + threadIdx.x) >> 6;
  int lane = threadIdx.x & 63;
  int nw = (gridDim.x * blockDim.x) >> 6;
  const int is64 = flag[0];
  for (int e = gw; e < E_EDGES; e += nw){
    int src, dst;
    if (is64){ src = ei[2 * e]; dst = ei[2 * E_EDGES + 2 * e]; }
    else     { src = ei[e];     dst = ei[E_EDGES + e]; }
    if ((unsigned)src >= N_NODES || (unsigned)dst >= N_NODES) continue;
    float2 v = *(const float2*)(x + (size_t)src * IN_DIM + 2 * lane);
    float* o = agg + (size_t)dst * IN_DIM + 2 * lane;
    unsafeAtomicAdd(o + 0, v.x);
    unsafeAtomicAdd(o + 1, v.y);
  }
}

// ---------------- K2: h = relu(agg @ Wb + bb) -> bf16; col-sums s ----------------
__global__ __launch_bounds__(256) void k_backbone(const float* __restrict__ agg,
                                                  const float* __restrict__ Wb,
                                                  const float* __restrict__ bb,
                                                  ushort_t* __restrict__ hbf,
                                                  float* __restrict__ s){
  __shared__ float WbS[32][256];
  __shared__ float aggS[32][36];
  int c = threadIdx.x;
  int n0 = blockIdx.x * 32;      // 625 blocks * 32 = 20000 exactly
  float acc[32];
  float bias = bb[c];
  #pragma unroll
  for (int i = 0; i < 32; i++) acc[i] = bias;
  for (int dc = 0; dc < 4; ++dc){
    __syncthreads();
    const float4* wsrc = (const float4*)(Wb + dc * 32 * 256);
    float4* wdst = (float4*)&WbS[0][0];
    #pragma unroll
    for (int i = 0; i < 8; i++) wdst[c + i * 256] = wsrc[c + i * 256];
    {
      int n = c >> 3, c4 = (c & 7) * 4;
      float4 v = *(const float4*)(agg + (size_t)(n0 + n) * IN_DIM + dc * 32 + c4);
      aggS[n][c4 + 0] = v.x; aggS[n][c4 + 1] = v.y;
      aggS[n][c4 + 2] = v.z; aggS[n][c4 + 3] = v.w;
    }
    __syncthreads();
    for (int d = 0; d < 32; ++d){
      float w = WbS[d][c];
      #pragma unroll
      for (int n = 0; n < 32; n++) acc[n] += aggS[n][d] * w;
    }
  }
  float ls = 0.f;
  #pragma unroll
  for (int n = 0; n < 32; n++){
    float hv = acc[n] > 0.f ? acc[n] : 0.f;
    ushort_t hb = f2bf(hv);
    hbf[(size_t)(n0 + n) * HID + c] = hb;
    ls += bf2f(hb);   // accumulate the rounded value for stat consistency
  }
  unsafeAtomicAdd(&s[c], ls);
}

// ---------------- K3: Gram G = h^T h (f32, split-K with atomics) ----------------
__global__ __launch_bounds__(256) void k_gram(const ushort_t* __restrict__ hbf,
                                              float* __restrict__ G){
  __shared__ float sA[16][68], sB[16][68];
  int t = threadIdx.x, tx = t & 15, ty = t >> 4;
  int ta = blockIdx.x >> 2, tb = blockIdx.x & 3;
  int ca = ta * 64, cb = tb * 64;
  int nbase = blockIdx.y * 800;   // 25 * 800 = 20000 exactly
  float acc[4][4] = {};
  for (int nb = 0; nb < 800; nb += 16){
    __syncthreads();
    {
      int row = t >> 4, c4 = (t & 15) * 4;
      const ushort_t* p = hbf + (size_t)(nbase + nb + row) * HID;
      ushort4 va = *(const ushort4*)(p + ca + c4);
      ushort4 vb = *(const ushort4*)(p + cb + c4);
      sA[row][c4+0]=bf2f(va.x); sA[row][c4+1]=bf2f(va.y); sA[row][c4+2]=bf2f(va.z); sA[row][c4+3]=bf2f(va.w);
      sB[row][c4+0]=bf2f(vb.x); sB[row][c4+1]=bf2f(vb.y); sB[row][c4+2]=bf2f(vb.z); sB[row][c4+3]=bf2f(vb.w);
    }
    __syncthreads();
    #pragma unroll
    for (int i = 0; i < 16; i++){
      float a0=sA[i][ty*4+0], a1=sA[i][ty*4+1], a2=sA[i][ty*4+2], a3=sA[i][ty*4+3];
      float b0=sB[i][tx*4+0], b1=sB[i][tx*4+1], b2=sB[i][tx*4+2], b3=sB[i][tx*4+3];
      acc[0][0]+=a0*b0; acc[0][1]+=a0*b1; acc[0][2]+=a0*b2; acc[0][3]+=a0*b3;
      acc[1][0]+=a1*b0; acc[1][1]+=a1*b1; acc[1][2]+=a1*b2; acc[1][3]+=a1*b3;
      acc[2][0]+=a2*b0; acc[2][1]+=a2*b1; acc[2][2]+=a2*b2; acc[2][3]+=a2*b3;
      acc[3][0]+=a3*b0; acc[3][1]+=a3*b1; acc[3][2]+=a3*b2; acc[3][3]+=a3*b3;
    }
  }
  #pragma unroll
  for (int p = 0; p < 4; p++)
    #pragma unroll
    for (int q = 0; q < 4; q++)
      unsafeAtomicAdd(&G[(size_t)(ca + ty*4 + p) * 256 + cb + tx*4 + q], acc[p][q]);
}

// ---------------- K5: transpose+convert W1->W1T, W2->W2T (bf16) ----------------
__global__ __launch_bounds__(256) void k_transpose(const float* __restrict__ W1,
                                                   const float* __restrict__ W2,
                                                   ushort_t* __restrict__ w1t,
                                                   ushort_t* __restrict__ w2t){
  __shared__ float tile[32][33];
  int which = blockIdx.z, h = blockIdx.y, b = blockIdx.x;
  const float* src; ushort_t* dst; int R, C;
  if (which == 0){ src = W1 + (size_t)h * 256 * 512; dst = w1t + (size_t)h * 512 * 256; R = 256; C = 512; }
  else           { src = W2 + (size_t)h * 512 * 256; dst = w2t + (size_t)h * 256 * 512; R = 512; C = 256; }
  int tcn = C >> 5;
  int tr = b / tcn, tc = b % tcn;
  int r0 = tr * 32, c0 = tc * 32;
  int tx = threadIdx.x & 31, ty = threadIdx.x >> 5;
  #pragma unroll
  for (int i = 0; i < 32; i += 8) tile[ty + i][tx] = src[(size_t)(r0 + ty + i) * C + c0 + tx];
  __syncthreads();
  #pragma unroll
  for (int i = 0; i < 32; i += 8) dst[(size_t)(c0 + ty + i) * R + r0 + tx] = f2bf(tile[tx][ty + i]);
}

// ---------------- K4: BN stats -> fold to a = relu(z*A + B) ----------------
__global__ __launch_bounds__(256) void k_stats(const float* __restrict__ G,
                                               const float* __restrict__ s,
                                               const ushort_t* __restrict__ w1t,
                                               const float* __restrict__ b1,
                                               const float* __restrict__ gamma,
                                               const float* __restrict__ beta,
                                               float* __restrict__ As,
                                               float* __restrict__ Bs){
  __shared__ ushort_t wL[256][64];   // wL[k][m] 32KB
  __shared__ float GL[16][256];      // 16KB
  __shared__ float sL[256];
  __shared__ float red[4][64];
  int h = blockIdx.y, m0 = blockIdx.x * 64;
  int t = threadIdx.x, m = t & 63, q = t >> 6;
  {
    int mm = t >> 2, part = t & 3;
    const ushort_t* src = w1t + ((size_t)h * 512 + m0 + mm) * 256 + part * 64;
    #pragma unroll
    for (int k4 = 0; k4 < 16; ++k4){
      ushort4 v = *(const ushort4*)(src + k4 * 4);
      int kb = part * 64 + k4 * 4;
      wL[kb+0][mm]=v.x; wL[kb+1][mm]=v.y; wL[kb+2][mm]=v.z; wL[kb+3][mm]=v.w;
    }
  }
  sL[t & 255] = s[t & 255];
  float quad = 0.f;
  for (int dc = 0; dc < 16; ++dc){
    __syncthreads();
    const float4* gs = (const float4*)(G + (size_t)dc * 16 * 256);
    float4* gd = (float4*)&GL[0][0];
    #pragma unroll
    for (int i = 0; i < 4; i++) gd[t + i * 256] = gs[t + i * 256];
    __syncthreads();
    #pragma unroll
    for (int i = 0; i < 4; i++){
      int dl = q * 4 + i;
      float wd = bf2f(wL[dc * 16 + dl][m]);
      float u = 0.f;
      for (int k = 0; k < 256; ++k) u += GL[dl][k] * bf2f(wL[k][m]);
      quad += wd * u;
    }
  }
  red[q][m] = quad;
  __syncthreads();
  if (q == 0){
    float qd = red[0][m] + red[1][m] + red[2][m] + red[3][m];
    float dot_s = 0.f;
    for (int k = 0; k < 256; ++k) dot_s += sL[k] * bf2f(wL[k][m]);
    float b1v = b1[(size_t)h * 512 + m0 + m];
    float invN = 1.f / (float)N_NODES;
    float mean = dot_s * invN + b1v;
    float ez2 = (qd + 2.f * b1v * dot_s) * invN + b1v * b1v;
    float var = ez2 - mean * mean;
    float rstd = rsqrtf(var + BN_EPS);
    float gv = gamma[(size_t)h * 512 + m0 + m];
    float be = beta[(size_t)h * 512 + m0 + m];
    float Av = rstd * gv;
    As[(size_t)h * 512 + m0 + m] = Av;
    Bs[(size_t)h * 512 + m0 + m] = be - mean * Av;
  }
}

// ---------------- K6: fused per-head GEMM1 -> BN/ReLU -> GEMM2 ----------------
__global__ __launch_bounds__(512) void k_main(const ushort_t* __restrict__ hbf,
                                              const ushort_t* __restrict__ w1t,
                                              const ushort_t* __restrict__ w2t,
                                              const float* __restrict__ As,
                                              const float* __restrict__ Bs,
                                              const float* __restrict__ b2,
                                              float* __restrict__ out){
  __shared__ __align__(16) ushort_t w1s[32 * 256];   // [m][d], XOR-swizzled 16B granules
  __shared__ __align__(16) ushort_t w2s[256 * 32];   // [dd][m], swizzled
  __shared__ __align__(16) ushort_t as_[128 * 32];   // [n][m], swizzled
  const int h = blockIdx.y;
  const int n0 = blockIdx.x * 128;
  const int t = threadIdx.x;
  const int w = t >> 6, l = t & 63;
  const int l15 = l & 15, l4 = l >> 4;
  const f32x4 fzero = {0.f, 0.f, 0.f, 0.f};
  const bf16x8 bzero = {0,0,0,0,0,0,0,0};

  bf16x8 afr[8];
  {
    int row = n0 + w * 16 + l15;
    const ushort_t* p = hbf + (size_t)row * HID + l4 * 8;
    #pragma unroll
    for (int kk = 0; kk < 8; kk++){
      bf16x8 v = bzero;
      if (row < N_NODES) v = *(const bf16x8*)(p + kk * 32);
      afr[kk] = v;
    }
  }
  f32x4 oacc[4][4];
  #pragma unroll
  for (int i = 0; i < 4; i++)
    #pragma unroll
    for (int j = 0; j < 4; j++) oacc[i][j] = fzero;

  const int wr = w >> 2, wc = w & 3;
  const float* Asp = As + (size_t)h * 512;
  const float* Bsp = Bs + (size_t)h * 512;
  const ushort_t* w1g = w1t + (size_t)h * 512 * 256;
  const ushort_t* w2g = w2t + (size_t)h * 256 * 512;

  for (int c = 0; c < 16; ++c){
    const int mc0 = c * 32;
    __syncthreads();
    #pragma unroll
    for (int i = 0; i < 2; i++){
      int gi = t + i * 512;
      int m = gi >> 5, g = gi & 31;
      uint4 v = *(const uint4*)(w1g + ((size_t)(mc0 + m)) * 256 + g * 8);
      *(uint4*)((char*)w1s + m * 512 + ((g ^ (m & 7)) * 16)) = v;
    }
    #pragma unroll
    for (int i = 0; i < 2; i++){
      int gi = t + i * 512;
      int dd = gi >> 2, g = gi & 3;
      uint4 v = *(const uint4*)(w2g + (size_t)dd * 512 + mc0 + g * 8);
      *(uint4*)((char*)w2s + dd * 64 + ((g ^ (dd & 3)) * 16)) = v;
    }
    __syncthreads();
    f32x4 zc[2];
    zc[0] = fzero; zc[1] = fzero;
    #pragma unroll
    for (int kk = 0; kk < 8; kk++){
      #pragma unroll
      for (int ct = 0; ct < 2; ct++){
        int m = ct * 16 + l15;
        int gr = kk * 4 + l4;
        bf16x8 bfr = *(const bf16x8*)((const char*)w1s + m * 512 + ((gr ^ (m & 7)) * 16));
        zc[ct] = __builtin_amdgcn_mfma_f32_16x16x32_bf16(afr[kk], bfr, zc[ct], 0, 0, 0);
      }
    }
    #pragma unroll
    for (int ct = 0; ct < 2; ct++){
      int ml = ct * 16 + l15;
      float Av = Asp[mc0 + ml];
      float Bv = Bsp[mc0 + ml];
      #pragma unroll
      for (int r = 0; r < 4; r++){
        int rowl = w * 16 + l4 * 4 + r;
        float a = zc[ct][r] * Av + Bv;
        a = a > 0.f ? a : 0.f;
        int g = ml >> 3;
        int byte_off = rowl * 64 + ((g ^ (rowl & 3)) * 16) + (ml & 7) * 2;
        *(ushort_t*)((char*)as_ + byte_off) = f2bf(a);
      }
    }
    __syncthreads();
    bf16x8 aa[4], bfr2[4];
    #pragma unroll
    for (int ri = 0; ri < 4; ri++){
      int row = wr * 64 + ri * 16 + l15;
      aa[ri] = *(const bf16x8*)((const char*)as_ + row * 64 + ((l4 ^ (row & 3)) * 16));
    }
    #pragma unroll
    for (int bt = 0; bt < 4; bt++){
      int dd = wc * 64 + bt * 16 + l15;
      bfr2[bt] = *(const bf16x8*)((const char*)w2s + dd * 64 + ((l4 ^ (dd & 3)) * 16));
    }
    #pragma unroll
    for (int ri = 0; ri < 4; ri++)
      #pragma unroll
      for (int bt = 0; bt < 4; bt++)
        oacc[ri][bt] = __builtin_amdgcn_mfma_f32_16x16x32_bf16(aa[ri], bfr2[bt], oacc[ri][bt], 0, 0, 0);
  }
  // ---- epilogue: out[n][h][dd] = oacc + b2 (FLOAT32 output) ----
  #pragma unroll
  for (int bt = 0; bt < 4; bt++){
    int dd = wc * 64 + bt * 16 + l15;
    float b2v = b2[(size_t)h * 256 + dd];
    #pragma unroll
    for (int ri = 0; ri < 4; ri++){
      #pragma unroll
      for (int r = 0; r < 4; r++){
        int n = n0 + wr * 64 + ri * 16 + l4 * 4 + r;
        if (n < N_NODES){
          out[((size_t)n * HEADS + h) * HID + dd] = oacc[ri][bt][r] + b2v;
        }
      }
    }
  }
}

extern "C" void kernel_launch(void* const* d_in, const int* in_sizes, int n_in,
                              void* d_out, int out_size, void* d_ws, size_t ws_size,
                              hipStream_t stream){
  const float* x     = (const float*)d_in[0];
  const int*   ei    = (const int*)  d_in[1];
  const float* Wb    = (const float*)d_in[2];
  const float* bb    = (const float*)d_in[3];
  const float* W1    = (const float*)d_in[4];
  const float* b1    = (const float*)d_in[5];
  const float* gamma = (const float*)d_in[6];
  const float* beta  = (const float*)d_in[7];
  const float* W2    = (const float*)d_in[8];
  const float* b2    = (const float*)d_in[9];
  float* out = (float*)d_out;

  char* ws = (char*)d_ws;
  size_t off = 0;
  auto alloc = [&](size_t bytes){ void* p = ws + off; off += (bytes + 255) & ~(size_t)255; return p; };
  float*    agg = (float*)   alloc((size_t)N_NODES * IN_DIM * 4);
  ushort_t* hbf = (ushort_t*)alloc((size_t)N_NODES * HID * 2);
  ushort_t* w1t = (ushort_t*)alloc((size_t)HEADS * MAXW * HID * 2);
  ushort_t* w2t = (ushort_t*)alloc((size_t)HEADS * HID * MAXW * 2);
  float*    G   = (float*)   alloc(256 * 256 * 4);
  float*    s   = (float*)   alloc(256 * 4);
  float*    As  = (float*)   alloc((size_t)HEADS * MAXW * 4);
  float*    Bs  = (float*)   alloc((size_t)HEADS * MAXW * 4);
  int*      flg = (int*)     alloc(256);

  hipLaunchKernelGGL(k_init,      dim3(1024),        dim3(256), 0, stream, x, agg, G, s);
  hipLaunchKernelGGL(k_detect,    dim3(1),           dim3(256), 0, stream, ei, flg);
  hipLaunchKernelGGL(k_transpose, dim3(128, 32, 2),  dim3(256), 0, stream, W1, W2, w1t, w2t);
  hipLaunchKernelGGL(k_edges,     dim3(1024),        dim3(256), 0, stream, x, ei, flg, agg);
  hipLaunchKernelGGL(k_backbone,  dim3(625),         dim3(256), 0, stream, agg, Wb, bb, hbf, s);
  hipLaunchKernelGGL(k_gram,      dim3(16, 25),      dim3(256), 0, stream, hbf, G);
  hipLaunchKernelGGL(k_stats,     dim3(8, 32),       dim3(256), 0, stream, G, s, w1t, b1, gamma, beta, As, Bs);
  hipLaunchKernelGGL(k_main,      dim3(157, 32),     dim3(512), 0, stream, hbf, w1t, w2t, As, Bs, b2, out);
}

// Round 4
// 1478.305 us; speedup vs baseline: 1.1455x; 1.1455x over previous
//
#include <hip/hip_runtime.h>
#include <stdint.h>

#define N_NODES 20000
#define E_EDGES 640000
#define IN_DIM  128
#define HID     256
#define MAXW    512
#define HEADS   32
#define BN_EPS  1e-5f

typedef __attribute__((ext_vector_type(8))) short bf16x8;
typedef __attribute__((ext_vector_type(4))) float f32x4;
typedef unsigned short ushort_t;

static __device__ __forceinline__ float bf2f(ushort_t u){
  union { unsigned int i; float f; } v; v.i = ((unsigned int)u) << 16; return v.f;
}
static __device__ __forceinline__ ushort_t f2bf(float f){
  union { float f; unsigned int i; } v; v.f = f;
  unsigned int r = v.i + 0x7fffu + ((v.i >> 16) & 1u);
  return (ushort_t)(r >> 16);
}

// ---------------- K0: init (agg = x, zero G and s) ----------------
__global__ void k_init(const float* __restrict__ x, float* __restrict__ agg,
                       float* __restrict__ G, float* __restrict__ s){
  int i = blockIdx.x * blockDim.x + threadIdx.x;
  int stride = gridDim.x * blockDim.x;
  const float4* xs = (const float4*)x;
  float4* ad = (float4*)agg;
  for (int j = i; j < N_NODES * IN_DIM / 4; j += stride) ad[j] = xs[j];
  float4 z4 = make_float4(0.f, 0.f, 0.f, 0.f);
  float4* Gd = (float4*)G;
  for (int j = i; j < 256 * 256 / 4; j += stride) Gd[j] = z4;
  if (i < 256) s[i] = 0.f;
}

// ---------------- K-detect: is edge_index stored as int64? ----------------
__global__ void k_detect(const int* __restrict__ ei, int* __restrict__ flag){
  __shared__ int any_nz;
  if (threadIdx.x == 0) any_nz = 0;
  __syncthreads();
  int nz = 0;
  for (int i = threadIdx.x; i < 4096; i += 256)
    if (ei[2 * i + 1] != 0) nz = 1;
  if (nz) atomicOr(&any_nz, 1);
  __syncthreads();
  if (threadIdx.x == 0) flag[0] = (any_nz == 0) ? 1 : 0;   // 1 => int64 layout
}

// ---------------- K1: edge scatter-add (atomics) ----------------
__global__ __launch_bounds__(256) void k_edges(const float* __restrict__ x,
                                               const int* __restrict__ ei,
                                               const int* __restrict__ flag,
                                               float* __restrict__ agg){
  int gw = (blockIdx.x * blockDim.x + threadIdx.x) >> 6;
  int lane = threadIdx.x & 63;
  int nw = (gridDim.x * blockDim.x) >> 6;
  const int is64 = flag[0];
  for (int e = gw; e < E_EDGES; e += nw){
    int src, dst;
    if (is64){ src = ei[2 * e]; dst = ei[2 * E_EDGES + 2 * e]; }
    else     { src = ei[e];     dst = ei[E_EDGES + e]; }
    if ((unsigned)src >= N_NODES || (unsigned)dst >= N_NODES) continue;
    float2 v = *(const float2*)(x + (size_t)src * IN_DIM + 2 * lane);
    float* o = agg + (size_t)dst * IN_DIM + 2 * lane;
    unsafeAtomicAdd(o + 0, v.x);
    unsafeAtomicAdd(o + 1, v.y);
  }
}

// ---------------- K2: h = relu(agg @ Wb + bb) -> bf16; col-sums s ----------------
__global__ __launch_bounds__(256) void k_backbone(const float* __restrict__ agg,
                                                  const float* __restrict__ Wb,
                                                  const float* __restrict__ bb,
                                                  ushort_t* __restrict__ hbf,
                                                  float* __restrict__ s){
  __shared__ float WbS[32][256];
  __shared__ float aggS[32][36];
  int c = threadIdx.x;
  int n0 = blockIdx.x * 32;      // 625 blocks * 32 = 20000 exactly
  float acc[32];
  float bias = bb[c];
  #pragma unroll
  for (int i = 0; i < 32; i++) acc[i] = bias;
  for (int dc = 0; dc < 4; ++dc){
    __syncthreads();
    const float4* wsrc = (const float4*)(Wb + dc * 32 * 256);
    float4* wdst = (float4*)&WbS[0][0];
    #pragma unroll
    for (int i = 0; i < 8; i++) wdst[c + i * 256] = wsrc[c + i * 256];
    {
      int n = c >> 3, c4 = (c & 7) * 4;
      float4 v = *(const float4*)(agg + (size_t)(n0 + n) * IN_DIM + dc * 32 + c4);
      aggS[n][c4 + 0] = v.x; aggS[n][c4 + 1] = v.y;
      aggS[n][c4 + 2] = v.z; aggS[n][c4 + 3] = v.w;
    }
    __syncthreads();
    for (int d = 0; d < 32; ++d){
      float w = WbS[d][c];
      #pragma unroll
      for (int n = 0; n < 32; n++) acc[n] += aggS[n][d] * w;
    }
  }
  float ls = 0.f;
  #pragma unroll
  for (int n = 0; n < 32; n++){
    float hv = acc[n] > 0.f ? acc[n] : 0.f;
    ushort_t hb = f2bf(hv);
    hbf[(size_t)(n0 + n) * HID + c] = hb;
    ls += bf2f(hb);   // accumulate the rounded value for stat consistency
  }
  unsafeAtomicAdd(&s[c], ls);
}

// ---------------- K3: Gram G = h^T h (f32, split-K with atomics) ----------------
__global__ __launch_bounds__(256) void k_gram(const ushort_t* __restrict__ hbf,
                                              float* __restrict__ G){
  __shared__ float sA[16][68], sB[16][68];
  int t = threadIdx.x, tx = t & 15, ty = t >> 4;
  int ta = blockIdx.x >> 2, tb = blockIdx.x & 3;
  int ca = ta * 64, cb = tb * 64;
  int nbase = blockIdx.y * 800;   // 25 * 800 = 20000 exactly
  float acc[4][4] = {};
  for (int nb = 0; nb < 800; nb += 16){
    __syncthreads();
    {
      int row = t >> 4, c4 = (t & 15) * 4;
      const ushort_t* p = hbf + (size_t)(nbase + nb + row) * HID;
      ushort4 va = *(const ushort4*)(p + ca + c4);
      ushort4 vb = *(const ushort4*)(p + cb + c4);
      sA[row][c4+0]=bf2f(va.x); sA[row][c4+1]=bf2f(va.y); sA[row][c4+2]=bf2f(va.z); sA[row][c4+3]=bf2f(va.w);
      sB[row][c4+0]=bf2f(vb.x); sB[row][c4+1]=bf2f(vb.y); sB[row][c4+2]=bf2f(vb.z); sB[row][c4+3]=bf2f(vb.w);
    }
    __syncthreads();
    #pragma unroll
    for (int i = 0; i < 16; i++){
      float a0=sA[i][ty*4+0], a1=sA[i][ty*4+1], a2=sA[i][ty*4+2], a3=sA[i][ty*4+3];
      float b0=sB[i][tx*4+0], b1=sB[i][tx*4+1], b2=sB[i][tx*4+2], b3=sB[i][tx*4+3];
      acc[0][0]+=a0*b0; acc[0][1]+=a0*b1; acc[0][2]+=a0*b2; acc[0][3]+=a0*b3;
      acc[1][0]+=a1*b0; acc[1][1]+=a1*b1; acc[1][2]+=a1*b2; acc[1][3]+=a1*b3;
      acc[2][0]+=a2*b0; acc[2][1]+=a2*b1; acc[2][2]+=a2*b2; acc[2][3]+=a2*b3;
      acc[3][0]+=a3*b0; acc[3][1]+=a3*b1; acc[3][2]+=a3*b2; acc[3][3]+=a3*b3;
    }
  }
  #pragma unroll
  for (int p = 0; p < 4; p++)
    #pragma unroll
    for (int q = 0; q < 4; q++)
      unsafeAtomicAdd(&G[(size_t)(ca + ty*4 + p) * 256 + cb + tx*4 + q], acc[p][q]);
}

// ---------------- K5: transpose+convert W1->W1T, W2->W2T (bf16) ----------------
__global__ __launch_bounds__(256) void k_transpose(const float* __restrict__ W1,
                                                   const float* __restrict__ W2,
                                                   ushort_t* __restrict__ w1t,
                                                   ushort_t* __restrict__ w2t){
  __shared__ float tile[32][33];
  int which = blockIdx.z, h = blockIdx.y, b = blockIdx.x;
  const float* src; ushort_t* dst; int R, C;
  if (which == 0){ src = W1 + (size_t)h * 256 * 512; dst = w1t + (size_t)h * 512 * 256; R = 256; C = 512; }
  else           { src = W2 + (size_t)h * 512 * 256; dst = w2t + (size_t)h * 256 * 512; R = 512; C = 256; }
  int tcn = C >> 5;
  int tr = b / tcn, tc = b % tcn;
  int r0 = tr * 32, c0 = tc * 32;
  int tx = threadIdx.x & 31, ty = threadIdx.x >> 5;
  #pragma unroll
  for (int i = 0; i < 32; i += 8) tile[ty + i][tx] = src[(size_t)(r0 + ty + i) * C + c0 + tx];
  __syncthreads();
  #pragma unroll
  for (int i = 0; i < 32; i += 8) dst[(size_t)(c0 + ty + i) * R + r0 + tx] = f2bf(tile[tx][ty + i]);
}

// ---------------- K4: BN stats -> fold to a = relu(z*A + B) ----------------
__global__ __launch_bounds__(256) void k_stats(const float* __restrict__ G,
                                               const float* __restrict__ s,
                                               const ushort_t* __restrict__ w1t,
                                               const float* __restrict__ b1,
                                               const float* __restrict__ gamma,
                                               const float* __restrict__ beta,
                                               float* __restrict__ As,
                                               float* __restrict__ Bs){
  __shared__ ushort_t wL[256][64];   // wL[k][m] 32KB
  __shared__ float GL[16][256];      // 16KB
  __shared__ float sL[256];
  __shared__ float red[4][64];
  int h = blockIdx.y, m0 = blockIdx.x * 64;
  int t = threadIdx.x, m = t & 63, q = t >> 6;
  {
    int mm = t >> 2, part = t & 3;
    const ushort_t* src = w1t + ((size_t)h * 512 + m0 + mm) * 256 + part * 64;
    #pragma unroll
    for (int k4 = 0; k4 < 16; ++k4){
      ushort4 v = *(const ushort4*)(src + k4 * 4);
      int kb = part * 64 + k4 * 4;
      wL[kb+0][mm]=v.x; wL[kb+1][mm]=v.y; wL[kb+2][mm]=v.z; wL[kb+3][mm]=v.w;
    }
  }
  sL[t & 255] = s[t & 255];
  float quad = 0.f;
  for (int dc = 0; dc < 16; ++dc){
    __syncthreads();
    const float4* gs = (const float4*)(G + (size_t)dc * 16 * 256);
    float4* gd = (float4*)&GL[0][0];
    #pragma unroll
    for (int i = 0; i < 4; i++) gd[t + i * 256] = gs[t + i * 256];
    __syncthreads();
    #pragma unroll
    for (int i = 0; i < 4; i++){
      int dl = q * 4 + i;
      float wd = bf2f(wL[dc * 16 + dl][m]);
      float u = 0.f;
      for (int k = 0; k < 256; ++k) u += GL[dl][k] * bf2f(wL[k][m]);
      quad += wd * u;
    }
  }
  red[q][m] = quad;
  __syncthreads();
  if (q == 0){
    float qd = red[0][m] + red[1][m] + red[2][m] + red[3][m];
    float dot_s = 0.f;
    for (int k = 0; k < 256; ++k) dot_s += sL[k] * bf2f(wL[k][m]);
    float b1v = b1[(size_t)h * 512 + m0 + m];
    float invN = 1.f / (float)N_NODES;
    float mean = dot_s * invN + b1v;
    float ez2 = (qd + 2.f * b1v * dot_s) * invN + b1v * b1v;
    float var = ez2 - mean * mean;
    float rstd = rsqrtf(var + BN_EPS);
    float gv = gamma[(size_t)h * 512 + m0 + m];
    float be = beta[(size_t)h * 512 + m0 + m];
    float Av = rstd * gv;
    As[(size_t)h * 512 + m0 + m] = Av;
    Bs[(size_t)h * 512 + m0 + m] = be - mean * Av;
  }
}

// ---------------- K6 v2: fused per-head GEMM1 -> BN/ReLU -> GEMM2 ----------------
// grid (79, 32), block 512 (8 waves). 256-node tile, m chunked by 32.
// Swapped-operand MFMAs: GEMM1 computes z^T (lane holds 4 consecutive m),
// GEMM2 computes out^T tile (lane holds 4 consecutive dd -> float4 stores).
// Double-buffered weight staging hides global latency under GEMM1.
__global__ __launch_bounds__(512, 2) void k_main(const ushort_t* __restrict__ hbf,
                                                 const ushort_t* __restrict__ w1t,
                                                 const ushort_t* __restrict__ w2t,
                                                 const float* __restrict__ As,
                                                 const float* __restrict__ Bs,
                                                 const float* __restrict__ b2,
                                                 float* __restrict__ out){
  __shared__ __align__(16) ushort_t w1s[2][32 * 256];   // [m][d] rows 512B, XOR-swizzled granules
  __shared__ __align__(16) ushort_t w2s[2][256 * 32];   // [dd][m] rows 64B, XOR-swizzled granules
  __shared__ __align__(16) ushort_t as_[256 * 40];      // [n][m] rows padded to 80B (conflict-free)
  const int h = blockIdx.y;
  const int n0 = blockIdx.x * 256;
  const int t = threadIdx.x;
  const int w = t >> 6, l = t & 63;
  const int l15 = l & 15, l4 = l >> 4;
  const int wr = w >> 1, wc = w & 1;   // GEMM2 wave tile: 64n x 128dd
  const f32x4 fzero = {0.f, 0.f, 0.f, 0.f};
  const bf16x8 bzero = {0,0,0,0,0,0,0,0};

  // h fragments: wave owns 32 nodes (2 sets of 16); invariant across chunks
  bf16x8 afr[2][8];
  #pragma unroll
  for (int nset = 0; nset < 2; nset++){
    int row = n0 + w * 32 + nset * 16 + l15;
    const ushort_t* p = hbf + (size_t)row * HID + l4 * 8;
    #pragma unroll
    for (int kk = 0; kk < 8; kk++){
      bf16x8 v = bzero;
      if (row < N_NODES) v = *(const bf16x8*)(p + kk * 32);
      afr[nset][kk] = v;
    }
  }
  f32x4 oacc[8][4];
  #pragma unroll
  for (int i = 0; i < 8; i++)
    #pragma unroll
    for (int j = 0; j < 4; j++) oacc[i][j] = fzero;

  const float* Asp = As + (size_t)h * 512;
  const float* Bsp = Bs + (size_t)h * 512;
  const ushort_t* w1g = w1t + (size_t)h * 512 * 256;
  const ushort_t* w2g = w2t + (size_t)h * 256 * 512;

  // prologue: stage chunk 0 into buffer 0
  {
    #pragma unroll
    for (int i = 0; i < 2; i++){
      int gi = t + i * 512;
      int m = gi >> 5, g = gi & 31;
      uint4 v = *(const uint4*)(w1g + (size_t)m * 256 + g * 8);
      *(uint4*)((char*)&w1s[0][0] + m * 512 + ((g ^ (m & 7)) * 16)) = v;
    }
    #pragma unroll
    for (int i = 0; i < 2; i++){
      int gi = t + i * 512;
      int dd = gi >> 2, g = gi & 3;
      uint4 v = *(const uint4*)(w2g + (size_t)dd * 512 + g * 8);
      *(uint4*)((char*)&w2s[0][0] + dd * 64 + ((g ^ (dd & 3)) * 16)) = v;
    }
  }
  __syncthreads();

  int cur = 0;
  for (int c = 0; c < 16; ++c){
    const int mc0 = c * 32;
    const bool pf = (c < 15);
    // issue next-chunk global loads early (consumed after barrier1)
    uint4 va0, va1, vb0, vb1;
    if (pf){
      const int mn = mc0 + 32;
      { int gi = t;       int m = gi >> 5, g = gi & 31; va0 = *(const uint4*)(w1g + (size_t)(mn + m) * 256 + g * 8); }
      { int gi = t + 512; int m = gi >> 5, g = gi & 31; va1 = *(const uint4*)(w1g + (size_t)(mn + m) * 256 + g * 8); }
      { int gi = t;       int dd = gi >> 2, g = gi & 3; vb0 = *(const uint4*)(w2g + (size_t)dd * 512 + mn + g * 8); }
      { int gi = t + 512; int dd = gi >> 2, g = gi & 3; vb1 = *(const uint4*)(w2g + (size_t)dd * 512 + mn + g * 8); }
    }
    // ---- GEMM1 (swapped): z^T[32m][16n x 2sets] per wave
    f32x4 zt[2][2];
    zt[0][0] = fzero; zt[0][1] = fzero; zt[1][0] = fzero; zt[1][1] = fzero;
    const char* w1b = (const char*)&w1s[cur][0];
    #pragma unroll
    for (int kk = 0; kk < 8; kk++){
      #pragma unroll
      for (int ct = 0; ct < 2; ct++){
        int m15 = ct * 16 + l15;
        int gr = kk * 4 + l4;
        bf16x8 bfr = *(const bf16x8*)(w1b + m15 * 512 + ((gr ^ (m15 & 7)) * 16));
        zt[0][ct] = __builtin_amdgcn_mfma_f32_16x16x32_bf16(bfr, afr[0][kk], zt[0][ct], 0, 0, 0);
        zt[1][ct] = __builtin_amdgcn_mfma_f32_16x16x32_bf16(bfr, afr[1][kk], zt[1][ct], 0, 0, 0);
      }
    }
    // ---- BN fold + ReLU -> as_ (packed b64 writes, padded rows)
    #pragma unroll
    for (int ct = 0; ct < 2; ct++){
      int mb = mc0 + ct * 16 + l4 * 4;
      float4 Av = *(const float4*)(Asp + mb);
      float4 Bv = *(const float4*)(Bsp + mb);
      #pragma unroll
      for (int nset = 0; nset < 2; nset++){
        float a0 = zt[nset][ct][0] * Av.x + Bv.x; a0 = a0 > 0.f ? a0 : 0.f;
        float a1 = zt[nset][ct][1] * Av.y + Bv.y; a1 = a1 > 0.f ? a1 : 0.f;
        float a2 = zt[nset][ct][2] * Av.z + Bv.z; a2 = a2 > 0.f ? a2 : 0.f;
        float a3 = zt[nset][ct][3] * Av.w + Bv.w; a3 = a3 > 0.f ? a3 : 0.f;
        uint2 pk;
        pk.x = (unsigned)f2bf(a0) | ((unsigned)f2bf(a1) << 16);
        pk.y = (unsigned)f2bf(a2) | ((unsigned)f2bf(a3) << 16);
        int nl = w * 32 + nset * 16 + l15;
        *(uint2*)((char*)as_ + nl * 80 + ct * 32 + l4 * 8) = pk;
      }
    }
    __syncthreads();   // barrier1: as_ ready; all reads of buf[cur^1] (prev chunk) long done
    // write prefetched weights into the other buffer
    if (pf){
      { int gi = t;       int m = gi >> 5, g = gi & 31; *(uint4*)((char*)&w1s[cur^1][0] + m * 512 + ((g ^ (m & 7)) * 16)) = va0; }
      { int gi = t + 512; int m = gi >> 5, g = gi & 31; *(uint4*)((char*)&w1s[cur^1][0] + m * 512 + ((g ^ (m & 7)) * 16)) = va1; }
      { int gi = t;       int dd = gi >> 2, g = gi & 3; *(uint4*)((char*)&w2s[cur^1][0] + dd * 64 + ((g ^ (dd & 3)) * 16)) = vb0; }
      { int gi = t + 512; int dd = gi >> 2, g = gi & 3; *(uint4*)((char*)&w2s[cur^1][0] + dd * 64 + ((g ^ (dd & 3)) * 16)) = vb1; }
    }
    // ---- GEMM2 (swapped): out^T tile 128dd x 64n per wave, K=32
    bf16x8 aa[4];
    #pragma unroll
    for (int ri = 0; ri < 4; ri++){
      int row = wr * 64 + ri * 16 + l15;
      aa[ri] = *(const bf16x8*)((const char*)as_ + row * 80 + l4 * 16);
    }
    const char* w2b = (const char*)&w2s[cur][0];
    #pragma unroll
    for (int bt = 0; bt < 8; bt++){
      int dd = wc * 128 + bt * 16 + l15;
      bf16x8 bf2r = *(const bf16x8*)(w2b + dd * 64 + ((l4 ^ (dd & 3)) * 16));
      #pragma unroll
      for (int ri = 0; ri < 4; ri++)
        oacc[bt][ri] = __builtin_amdgcn_mfma_f32_16x16x32_bf16(bf2r, aa[ri], oacc[bt][ri], 0, 0, 0);
    }
    __syncthreads();   // barrier2: GEMM2 reads done; staged buffer complete
    cur ^= 1;
  }
  // ---- epilogue: out[n][h][dd..dd+3] float4 stores
  #pragma unroll
  for (int bt = 0; bt < 8; bt++){
    int dd = wc * 128 + bt * 16 + l4 * 4;
    float4 b2v = *(const float4*)(b2 + (size_t)h * 256 + dd);
    #pragma unroll
    for (int ri = 0; ri < 4; ri++){
      int n = n0 + wr * 64 + ri * 16 + l15;
      if (n < N_NODES){
        float4 v;
        v.x = oacc[bt][ri][0] + b2v.x;
        v.y = oacc[bt][ri][1] + b2v.y;
        v.z = oacc[bt][ri][2] + b2v.z;
        v.w = oacc[bt][ri][3] + b2v.w;
        *(float4*)(out + (size_t)n * (HEADS * HID) + h * HID + dd) = v;
      }
    }
  }
}

extern "C" void kernel_launch(void* const* d_in, const int* in_sizes, int n_in,
                              void* d_out, int out_size, void* d_ws, size_t ws_size,
                              hipStream_t stream){
  const float* x     = (const float*)d_in[0];
  const int*   ei    = (const int*)  d_in[1];
  const float* Wb    = (const float*)d_in[2];
  const float* bb    = (const float*)d_in[3];
  const float* W1    = (const float*)d_in[4];
  const float* b1    = (const float*)d_in[5];
  const float* gamma = (const float*)d_in[6];
  const float* beta  = (const float*)d_in[7];
  const float* W2    = (const float*)d_in[8];
  const float* b2    = (const float*)d_in[9];
  float* out = (float*)d_out;

  char* ws = (char*)d_ws;
  size_t off = 0;
  auto alloc = [&](size_t bytes){ void* p = ws + off; off += (bytes + 255) & ~(size_t)255; return p; };
  float*    agg = (float*)   alloc((size_t)N_NODES * IN_DIM * 4);
  ushort_t* hbf = (ushort_t*)alloc((size_t)N_NODES * HID * 2);
  ushort_t* w1t = (ushort_t*)alloc((size_t)HEADS * MAXW * HID * 2);
  ushort_t* w2t = (ushort_t*)alloc((size_t)HEADS * HID * MAXW * 2);
  float*    G   = (float*)   alloc(256 * 256 * 4);
  float*    s   = (float*)   alloc(256 * 4);
  float*    As  = (float*)   alloc((size_t)HEADS * MAXW * 4);
  float*    Bs  = (float*)   alloc((size_t)HEADS * MAXW * 4);
  int*      flg = (int*)     alloc(256);

  hipLaunchKernelGGL(k_init,      dim3(1024),        dim3(256), 0, stream, x, agg, G, s);
  hipLaunchKernelGGL(k_detect,    dim3(1),           dim3(256), 0, stream, ei, flg);
  hipLaunchKernelGGL(k_transpose, dim3(128, 32, 2),  dim3(256), 0, stream, W1, W2, w1t, w2t);
  hipLaunchKernelGGL(k_edges,     dim3(1024),        dim3(256), 0, stream, x, ei, flg, agg);
  hipLaunchKernelGGL(k_backbone,  dim3(625),         dim3(256), 0, stream, agg, Wb, bb, hbf, s);
  hipLaunchKernelGGL(k_gram,      dim3(16, 25),      dim3(256), 0, stream, hbf, G);
  hipLaunchKernelGGL(k_stats,     dim3(8, 32),       dim3(256), 0, stream, G, s, w1t, b1, gamma, beta, As, Bs);
  hipLaunchKernelGGL(k_main,      dim3(79, 32),      dim3(512), 0, stream, hbf, w1t, w2t, As, Bs, b2, out);
}